// Round 5
// baseline (203.835 us; speedup 1.0000x reference)
//
#include <hip/hip_runtime.h>
#include <math.h>

#define TOTAL_G 17064
#define BATCHN  16
#define ALLF    0xFFFFFFFFFFFFFFFFull
// valid <=> score > 0.01f <=> scorebits > 0x3C23D70A <=> (key>>15) < 0xC3DC28F5
#define INVALID_HI 0xC3DC28F5u

typedef unsigned long long u64;
typedef unsigned int u32;

// ---- ws layout (bytes), total 4,306,432 ----
#define KEYS0_OFF   0          // u64[16][12800]  1,638,400
#define KEYS1_OFF   1638400    // u64[16][3200]     409,600
#define KEYS234_OFF 2048000    // u64[16][1088]     139,264
#define CLSI_OFF    2187264    // u16[16][17064]    546,048
#define NC_OFF      2733312    // int[16] (+pad)        256
#define CK_OFF      2733568    // u64[16][3072]     393,216
#define KR_OFF      3126784    // u64[16][3072]     393,216
#define BOX_OFF     3520000    // f4 [16][3072]     786,432

struct Ptrs {
  const float *cls0,*cls1,*cls2,*cls3,*cls4;
  const float *reg0,*reg1,*reg2,*reg3,*reg4;
  const float *ctr0,*ctr1,*ctr2,*ctr3,*ctr4;
  const float *pos0,*pos1,*pos2,*pos3,*pos4;
  char *ws;
};

__device__ __forceinline__ float sigd(float x) {
  return (float)(1.0 / (1.0 + exp(-(double)x)));
}
__device__ __forceinline__ float dexp(float x) {
  return (float)exp((double)x);
}
__device__ __forceinline__ void levinfo(int gid, int& lev, int& idx, int& nl) {
  if      (gid < 12800) { lev=0; idx=gid;        nl=12800; }
  else if (gid < 16000) { lev=1; idx=gid-12800;  nl=3200;  }
  else if (gid < 16800) { lev=2; idx=gid-16000;  nl=800;   }
  else if (gid < 17008) { lev=3; idx=gid-16800;  nl=208;   }
  else                  { lev=4; idx=gid-17008;  nl=56;    }
}

__device__ __forceinline__ u64* ckeys_of(char* ws, int b) {
  return (u64*)(ws + CK_OFF + (size_t)b * 24576);
}
__device__ __forceinline__ u64* krank_of(char* ws, int b) {
  return (u64*)(ws + KR_OFF + (size_t)b * 24576);
}
__device__ __forceinline__ float4* boxes_of(char* ws, int b) {
  return (float4*)(ws + BOX_OFF + (size_t)b * 49152);
}

// ---------------- K1: 4-threads-per-position score / argmax / key ----------------
__global__ __launch_bounds__(256) void k_score(Ptrs P) {
  int t = blockIdx.x * 256 + threadIdx.x;
  int g = t >> 2, q = t & 3;            // position, quarter (20 classes each)
  if (g >= TOTAL_G) return;
  int b = blockIdx.y;

  int lev, idx, nl;
  levinfo(g, lev, idx, nl);
  const float *clsb, *ctrb;
  if      (lev == 0) { clsb = P.cls0; ctrb = P.ctr0; }
  else if (lev == 1) { clsb = P.cls1; ctrb = P.ctr1; }
  else if (lev == 2) { clsb = P.cls2; ctrb = P.ctr2; }
  else if (lev == 3) { clsb = P.cls3; ctrb = P.ctr3; }
  else               { clsb = P.cls4; ctrb = P.ctr4; }

  const float4* cp4 = (const float4*)(clsb + (size_t)(b * nl + idx) * 80) + q * 5;
  // local top-2 over this thread's 20 classes (indices q*20 + 0..19)
  float m = -INFINITY, m2 = -INFINITY; int mi = 0;
  #pragma unroll
  for (int k = 0; k < 5; ++k) {
    float4 v = cp4[k];
    int base = q * 20 + 4 * k;
    if (v.x > m) { m2 = m; m = v.x; mi = base+0; } else if (v.x > m2) m2 = v.x;
    if (v.y > m) { m2 = m; m = v.y; mi = base+1; } else if (v.y > m2) m2 = v.y;
    if (v.z > m) { m2 = m; m = v.z; mi = base+2; } else if (v.z > m2) m2 = v.z;
    if (v.w > m) { m2 = m; m = v.w; mi = base+3; } else if (v.w > m2) m2 = v.w;
  }
  // merge top-2 across the 4-lane group (first-index tie-break preserved)
  #pragma unroll
  for (int xw = 1; xw <= 2; xw <<= 1) {
    float om  = __shfl_xor(m,  xw);
    float om2 = __shfl_xor(m2, xw);
    int   omi = __shfl_xor(mi, xw);
    bool take = (om > m) || (om == m && omi < mi);
    float lm  = take ? m : om;          // losing max
    float wm2 = take ? om2 : m2;        // winner's second
    if (take) { m = om; mi = omi; }
    m2 = fmaxf(lm, wm2);
  }

  // sigmoid-tie candidate band (same proven logic: multiple candidates <=> m2 >= thr)
  float thr = fminf(m - 1e-3f, 9.0f);
  float pmax; int ci;
  if (m2 >= thr) {
    // rare exact path: per-element sigmoid argmax among candidates >= thr
    float pv = -1.0f; int pi = 0x7fffffff;
    #pragma unroll 1
    for (int k = 0; k < 5; ++k) {
      float4 v = cp4[k];
      float xs[4] = {v.x, v.y, v.z, v.w};
      #pragma unroll
      for (int e = 0; e < 4; ++e) {
        if (xs[e] >= thr) {
          float p = sigd(xs[e]);
          if (p > pv) { pv = p; pi = q * 20 + 4 * k + e; }
        }
      }
    }
    #pragma unroll
    for (int xw = 1; xw <= 2; xw <<= 1) {
      float ov = __shfl_xor(pv, xw);
      int   oi = __shfl_xor(pi, xw);
      if (ov > pv || (ov == pv && oi < pi)) { pv = ov; pi = oi; }
    }
    pmax = pv; ci = pi;
  } else {
    pmax = sigd(m); ci = mi;
  }

  if (q == 0) {
    float tc = ctrb[(size_t)b * nl + idx];
    float csig = sigd(tc);
    float prod = pmax * csig;
    float s = (float)sqrt((double)prod);
    ((unsigned short*)(P.ws + CLSI_OFF))[(size_t)b * TOTAL_G + g] = (unsigned short)ci;
    unsigned hi = ~__float_as_uint(s);
    u64 key = ((u64)hi << 15) | (unsigned)g;   // global NMS-order key
    if      (lev == 0) ((u64*)(P.ws + KEYS0_OFF))  [(size_t)b * 12800 + idx] = key;
    else if (lev == 1) ((u64*)(P.ws + KEYS1_OFF))  [(size_t)b * 3200  + idx] = key;
    else               ((u64*)(P.ws + KEYS234_OFF))[(size_t)b * 1088  + (g - 16000)] = key;
  }
}

// ---------------- radix-select: exact 1000th-smallest 47-bit key ----------------
__device__ u64 radix_select(const u64* keys, int n,
                            u32 (*hist)[4096], u64* bcastP, int* bcastT) {
  int tid = threadIdx.x, wid = tid >> 6, lane = tid & 63;
  int rep = wid & 7;
  u64 Pfx = 0; int t = 1000;
  const int S[4] = {35, 23, 11, 0};
  const int W[4] = {12, 12, 12, 11};
  #pragma unroll 1
  for (int p = 0; p < 4; ++p) {
    int s = S[p], wb = W[p];
    u32 dmask = (1u << wb) - 1u;
    for (int i = tid; i < 8 * 4096; i += 1024) (&hist[0][0])[i] = 0;
    __syncthreads();
    for (int i = tid; i < n; i += 1024) {
      u64 k = keys[i];
      if ((k >> (s + wb)) == Pfx) {
        u32 d = (u32)(k >> s) & dmask;
        atomicAdd(&hist[rep][d], 1u);
      }
    }
    __syncthreads();
    for (int i = tid; i < 4096; i += 1024) {
      u32 v = hist[0][i];
      #pragma unroll
      for (int r = 1; r < 8; ++r) v += hist[r][i];
      hist[0][i] = v;
    }
    __syncthreads();
    if (wid == 0) {
      u32 ssum = 0;
      #pragma unroll 8
      for (int i = 0; i < 64; ++i) {
        int ii = (i + lane) & 63;
        ssum += hist[0][(lane << 6) + ii];
      }
      u32 inc = ssum;
      for (int o = 1; o < 64; o <<= 1) {
        u32 v = __shfl_up(inc, o);
        if (lane >= o) inc += v;
      }
      u64 ball = __ballot(inc >= (u32)t);
      int Ws = __ffsll(ball) - 1;
      u32 cumBefore = __shfl(inc - ssum, Ws);
      u32 v2 = hist[0][(Ws << 6) + lane];
      u32 inc2 = v2;
      for (int o = 1; o < 64; o <<= 1) {
        u32 x = __shfl_up(inc2, o);
        if (lane >= o) inc2 += x;
      }
      u64 ball2 = __ballot(cumBefore + inc2 >= (u32)t);
      int l2 = __ffsll(ball2) - 1;
      u32 cumB2 = __shfl(cumBefore + inc2 - v2, l2);
      if (lane == 0) {
        int d = (Ws << 6) + l2;
        *bcastP = (Pfx << wb) | (u32)d;
        *bcastT = t - (int)cumB2;
      }
    }
    __syncthreads();
    Pfx = *bcastP; t = *bcastT;
    __syncthreads();
  }
  return Pfx;
}

__device__ __forceinline__ u64 loadkey(const Ptrs& P, int b, int u) {
  if (u < 12800) return ((const u64*)(P.ws + KEYS0_OFF))  [(size_t)b * 12800 + u];
  if (u < 16000) return ((const u64*)(P.ws + KEYS1_OFF))  [(size_t)b * 3200  + (u - 12800)];
  return               ((const u64*)(P.ws + KEYS234_OFF))[(size_t)b * 1088  + (u - 16000)];
}

// ---------------- K2: per-image select thresholds + compact (16 blocks) ----------------
__global__ __launch_bounds__(1024) void k_selcomp(Ptrs P) {
  __shared__ u32 hist[8][4096];       // 128 KB
  __shared__ u64 bcastP;
  __shared__ int bcastT;
  __shared__ int wbase[17 * 16 + 1];
  int b = blockIdx.x;
  int tid = threadIdx.x, wid = tid >> 6, lane = tid & 63;

  u64 T0 = radix_select((const u64*)(P.ws + KEYS0_OFF) + (size_t)b * 12800, 12800,
                        hist, &bcastP, &bcastT);
  u64 T1 = radix_select((const u64*)(P.ws + KEYS1_OFF) + (size_t)b * 3200, 3200,
                        hist, &bcastP, &bcastT);

  // deterministic ballot compaction of survivors
  for (int it = 0; it < 17; ++it) {
    int u = it * 1024 + tid;
    bool keep = false;
    if (u < TOTAL_G) {
      u64 k = loadkey(P, b, u);
      bool valid = (u32)(k >> 15) < INVALID_HI;
      bool sel = (u < 12800) ? (k <= T0) : ((u < 16000) ? (k <= T1) : true);
      keep = valid && sel;
    }
    u64 bal = __ballot(keep);
    if (lane == 0) wbase[it * 16 + wid] = __popcll(bal);
  }
  __syncthreads();
  if (tid == 0) {
    int run = 0;
    for (int i = 0; i < 272; ++i) { int c = wbase[i]; wbase[i] = run; run += c; }
    ((int*)(P.ws + NC_OFF))[b] = run;
  }
  __syncthreads();
  u64* ck = ckeys_of(P.ws, b);
  for (int it = 0; it < 17; ++it) {
    int u = it * 1024 + tid;
    bool keep = false; u64 k = 0;
    if (u < TOTAL_G) {
      k = loadkey(P, b, u);
      bool valid = (u32)(k >> 15) < INVALID_HI;
      bool sel = (u < 12800) ? (k <= T0) : ((u < 16000) ? (k <= T1) : true);
      keep = valid && sel;
    }
    u64 bal = __ballot(keep);
    int pos = wbase[it * 16 + wid] + __popcll(bal & ((1ull << lane) - 1ull));
    if (keep) ck[pos] = k;
  }
}

// ---------------- K3: rank-by-counting + box decode (12 x 16 blocks) ----------------
__global__ __launch_bounds__(1024) void k_rankdecode(Ptrs P) {
  __shared__ u64 skey[3072];
  __shared__ unsigned short parts[1024];
  int part = blockIdx.x, b = blockIdx.y;
  int tid = threadIdx.x;
  int Nc = ((int*)(P.ws + NC_OFF))[b];
  const u64* ck = ckeys_of(P.ws, b);
  for (int t = tid; t < Nc; t += 1024) skey[t] = ck[t];
  __syncthreads();

  int ci = (part << 8) + (tid & 255);
  int seg = tid >> 8;
  u64 my = (ci < Nc) ? skey[ci] : ALLF;
  int jlen = (Nc + 3) >> 2;
  int jb = seg * jlen;
  int je = jb + jlen; if (je > Nc) je = Nc;
  int cnt = 0;
  #pragma unroll 4
  for (int j = jb; j < je; ++j) cnt += (skey[j] < my) ? 1 : 0;
  parts[tid] = (unsigned short)cnt;
  __syncthreads();

  if (seg == 0 && ci < Nc) {
    int r = cnt + parts[tid + 256] + parts[tid + 512] + parts[tid + 768];
    int gid = (int)(my & 0x7FFF);
    int lev, idx, nl; levinfo(gid, lev, idx, nl);
    const float *rp, *pp;
    if      (lev == 0) { rp = P.reg0; pp = P.pos0; }
    else if (lev == 1) { rp = P.reg1; pp = P.pos1; }
    else if (lev == 2) { rp = P.reg2; pp = P.pos2; }
    else if (lev == 3) { rp = P.reg3; pp = P.pos3; }
    else               { rp = P.reg4; pp = P.pos4; }
    float4 rv = *(const float4*)(rp + (size_t)(b * nl + idx) * 4);
    float2 pv = *(const float2*)(pp + (size_t)(b * nl + idx) * 2);
    float e0 = dexp(rv.x), e1 = dexp(rv.y), e2 = dexp(rv.z), e3 = dexp(rv.w);
    float x1 = truncf(pv.x - e0), y1 = truncf(pv.y - e1);
    float x2 = truncf(pv.x + e2), y2 = truncf(pv.y + e3);
    x1 = fmaxf(x1, 0.0f); y1 = fmaxf(y1, 0.0f);
    x2 = fminf(x2, 1023.0f); y2 = fminf(y2, 799.0f);
    boxes_of(P.ws, b)[r] = make_float4(x1, y1, x2, y2);
    krank_of(P.ws, b)[r] = my;
  }
}

// ---------------- K4: in-LDS mask + greedy reduce + outputs (16 blocks) ----------------
__global__ __launch_bounds__(1024) void k_finish(Ptrs P, float* out) {
  __shared__ float4 sbox[512];
  __shared__ u64 smask[4096];       // 32 KB
  __shared__ u64 live48[48];
  __shared__ unsigned short keeplist[100];
  __shared__ int slotgid[100];
  __shared__ int keptS, curS;
  int b = blockIdx.x;
  int tid = threadIdx.x;
  char* ws = P.ws;
  int Nc = ((int*)(ws + NC_OFF))[b];
  const float4* boxes4 = boxes_of(ws, b);

  if (tid < 512)
    sbox[tid] = (tid < Nc) ? boxes4[tid] : make_float4(-1e30f, -1e30f, -1e30f, -1e30f);
  if (tid < 48) {
    int lo = tid << 6;
    int c = Nc - lo; if (c < 0) c = 0; if (c > 64) c = 64;
    live48[tid] = (c >= 64) ? ALLF : ((c > 0) ? ((1ull << c) - 1ull) : 0ull);
  }
  __syncthreads();

  // suppression mask for top-512 ranks, built directly in LDS (rotated j-scan)
  int w = tid & 7;
  #pragma unroll 1
  for (int qi = 0; qi < 4; ++qi) {
    int i = qi * 128 + (tid >> 3);
    float4 bi = sbox[i];
    float ia = (bi.z - bi.x) * (bi.w - bi.y);
    u64 mword = 0;
    #pragma unroll 8
    for (int bj = 0; bj < 64; ++bj) {
      int jj = (bj + w) & 63;
      int j = (w << 6) | jj;
      if (j > i) {
        float4 bj4 = sbox[j];
        float ja  = (bj4.z - bj4.x) * (bj4.w - bj4.y);
        float ltx = fmaxf(bi.x, bj4.x), lty = fmaxf(bi.y, bj4.y);
        float rbx = fminf(bi.z, bj4.z), rby = fminf(bi.w, bj4.w);
        float wv = fmaxf(rbx - ltx, 0.0f), hv = fmaxf(rby - lty, 0.0f);
        float inter = wv * hv;
        float iou = inter / (ia + ja - inter);   // exact: integer-valued fp32
        if (iou > 0.6f) mword |= (1ull << jj);
      }
    }
    smask[i * 8 + w] = mword;
  }
  __syncthreads();

  // single-wave barrier-free greedy reduce over ranks [0,512)
  if (tid < 64) {
    int lane = tid;
    int n512 = (Nc < 512) ? Nc : 512;
    u64 lw = 0;
    if (lane < 8) {
      int lo = lane << 6;
      int c = n512 - lo; if (c < 0) c = 0; if (c > 64) c = 64;
      lw = (c >= 64) ? ALLF : ((c > 0) ? ((1ull << c) - 1ull) : 0ull);
    }
    int kept = 0;
    while (kept < 100) {
      bool nz = (lane < 8) && (lw != 0ull);
      u64 bal = __ballot(nz);
      if (!bal) break;
      int W = __ffsll(bal) - 1;
      u64 wv = __shfl(lw, W);
      int bit = __ffsll(wv) - 1;
      int i = (W << 6) + bit;
      if (lane == 0) keeplist[kept] = (unsigned short)i;
      kept++;
      if (lane == W) lw &= ~(1ull << bit);
      if (kept == 100) break;
      if (lane < 8) lw &= ~smask[i * 8 + lane];
    }
    if (lane == 0) keptS = kept;
  }
  __syncthreads();
  int kept = keptS;

  // fallback: 100th keep beyond rank 512 (rare; exact)
  if (kept < 100 && Nc > 512) {
    for (int k2 = 0; k2 < kept; ++k2) {
      int i = keeplist[k2];
      float4 bi = sbox[i];
      float ia = (bi.z - bi.x) * (bi.w - bi.y);
      for (int j = 512 + tid; j < Nc; j += 1024) {
        if (!((live48[j >> 6] >> (j & 63)) & 1ull)) continue;
        float4 bj4 = boxes4[j];
        float ja  = (bj4.z - bj4.x) * (bj4.w - bj4.y);
        float ltx = fmaxf(bi.x, bj4.x), lty = fmaxf(bi.y, bj4.y);
        float rbx = fminf(bi.z, bj4.z), rby = fminf(bi.w, bj4.w);
        float wv = fmaxf(rbx - ltx, 0.0f), hv = fmaxf(rby - lty, 0.0f);
        float inter = wv * hv;
        float iou = inter / (ia + ja - inter);
        if (iou > 0.6f) atomicAnd(&live48[j >> 6], ~(1ull << (j & 63)));
      }
    }
    __syncthreads();
    int start = 512;
    while (kept < 100) {
      if (tid == 0) {
        int nxt = -1;
        int wq = start >> 6;
        u64 mk = (wq < 48) ? (live48[wq] & (~0ull << (start & 63))) : 0ull;
        while (wq < 48) {
          if (mk) { nxt = (wq << 6) + __ffsll(mk) - 1; break; }
          ++wq;
          if (wq < 48) mk = live48[wq];
        }
        curS = nxt;
        if (nxt >= 0) keeplist[kept] = (unsigned short)nxt;
      }
      __syncthreads();
      int i = curS;
      if (i < 0) break;
      float4 bi = (i < 512) ? sbox[i] : boxes4[i];
      float ia = (bi.z - bi.x) * (bi.w - bi.y);
      for (int j = i + 1 + tid; j < Nc; j += 1024) {
        if (!((live48[j >> 6] >> (j & 63)) & 1ull)) continue;
        float4 bj4 = boxes4[j];
        float ja  = (bj4.z - bj4.x) * (bj4.w - bj4.y);
        float ltx = fmaxf(bi.x, bj4.x), lty = fmaxf(bi.y, bj4.y);
        float rbx = fminf(bi.z, bj4.z), rby = fminf(bi.w, bj4.w);
        float wv = fmaxf(rbx - ltx, 0.0f), hv = fmaxf(rby - lty, 0.0f);
        float inter = wv * hv;
        float iou = inter / (ia + ja - inter);
        if (iou > 0.6f) atomicAnd(&live48[j >> 6], ~(1ull << (j & 63)));
      }
      __syncthreads();
      kept++;
      start = i + 1;
    }
  }

  // outputs: out_s @0 [16,100], out_c @1600, out_b @3200 [16,100,4], out_cp @9600
  const u64* kr = krank_of(ws, b);
  if (tid < 100) {
    int s = tid;
    float os = -1.0f, oc = -1.0f;
    float4 bx = make_float4(-1.0f, -1.0f, -1.0f, -1.0f);
    int gid = -1;
    if (s < kept) {
      int r = keeplist[s];
      u64 key = kr[r];
      gid = (int)(key & 0x7FFF);
      os = __uint_as_float(~(u32)(key >> 15));
      oc = (float)((unsigned short*)(ws + CLSI_OFF))[(size_t)b * TOTAL_G + gid];
      bx = (r < 512) ? sbox[r] : boxes4[r];
    }
    slotgid[s] = gid;
    out[b * 100 + s] = os;
    out[1600 + b * 100 + s] = oc;
    *(float4*)(out + 3200 + (size_t)(b * 100 + s) * 4) = bx;
  }
  __syncthreads();
  for (int t = tid; t < 100 * 80; t += 1024) {
    int s = t / 80, k = t - s * 80;
    float val = -1.0f;
    int gid = slotgid[s];
    if (gid >= 0) {
      int lev, idx, nl; levinfo(gid, lev, idx, nl);
      const float* cp;
      if      (lev == 0) cp = P.cls0;
      else if (lev == 1) cp = P.cls1;
      else if (lev == 2) cp = P.cls2;
      else if (lev == 3) cp = P.cls3;
      else               cp = P.cls4;
      val = sigd(cp[(size_t)(b * nl + idx) * 80 + k]);
    }
    out[9600 + (size_t)(b * 100 + s) * 80 + k] = val;
  }
}

extern "C" void kernel_launch(void* const* d_in, const int* in_sizes, int n_in,
                              void* d_out, int out_size, void* d_ws, size_t ws_size,
                              hipStream_t stream) {
  (void)in_sizes; (void)n_in; (void)out_size; (void)ws_size;
  Ptrs P;
  P.cls0 = (const float*)d_in[0];  P.reg0 = (const float*)d_in[1];
  P.ctr0 = (const float*)d_in[2];  P.pos0 = (const float*)d_in[3];
  P.cls1 = (const float*)d_in[4];  P.reg1 = (const float*)d_in[5];
  P.ctr1 = (const float*)d_in[6];  P.pos1 = (const float*)d_in[7];
  P.cls2 = (const float*)d_in[8];  P.reg2 = (const float*)d_in[9];
  P.ctr2 = (const float*)d_in[10]; P.pos2 = (const float*)d_in[11];
  P.cls3 = (const float*)d_in[12]; P.reg3 = (const float*)d_in[13];
  P.ctr3 = (const float*)d_in[14]; P.pos3 = (const float*)d_in[15];
  P.cls4 = (const float*)d_in[16]; P.reg4 = (const float*)d_in[17];
  P.ctr4 = (const float*)d_in[18]; P.pos4 = (const float*)d_in[19];
  P.ws = (char*)d_ws;

  // 4 threads per position: 17064*4 = 68256 threads per image
  k_score<<<dim3(267, 16), 256, 0, stream>>>(P);
  k_selcomp<<<16, 1024, 0, stream>>>(P);
  k_rankdecode<<<dim3(12, 16), 1024, 0, stream>>>(P);
  k_finish<<<16, 1024, 0, stream>>>(P, (float*)d_out);
}